// Round 4
// baseline (215.864 us; speedup 1.0000x reference)
//
#include <hip/hip_runtime.h>

typedef __bf16 bf16_t;
typedef __bf16 bf16x8 __attribute__((ext_vector_type(8)));
typedef float f32x4 __attribute__((ext_vector_type(4)));
typedef unsigned short u16x4_t __attribute__((ext_vector_type(4)));

#define HW 16384
#define LOG2E 1.44269504088896f

__device__ __forceinline__ bf16_t f2b(float f) {
  unsigned u = __builtin_bit_cast(unsigned, f);
  u += 0x7fff + ((u >> 16) & 1);              // RTN-even
  unsigned short s = (unsigned short)(u >> 16);
  return __builtin_bit_cast(bf16_t, s);
}
__device__ __forceinline__ unsigned short b2u(bf16_t b) {
  return __builtin_bit_cast(unsigned short, b);
}

// ---------------- Phase 1: Q/V/K 1x1-conv, M=p layout, direct reg->global stores ----------
// D[p][o] = sum_c x^T[p,c] * W[o,c];  C/D: col(N)=o=lane&15(+16nt), row(M)=p=4*(lane>>4)+r(+16mt)
__global__ __launch_bounds__(256, 3) void qvk_kernel(
    const float* __restrict__ x, const float* __restrict__ e,
    const float* __restrict__ W1, const float* __restrict__ b1,
    const float* __restrict__ W2, const float* __restrict__ b2,
    const float* __restrict__ W3, const float* __restrict__ b3,
    bf16_t* __restrict__ Qg, bf16_t* __restrict__ Vg, bf16_t* __restrict__ Kg)
{
  __shared__ bf16_t lx[256 * 64];    // x^T tile [p][c], 128B rows, XOR swizzle (32 KiB)
  __shared__ bf16_t le[256 * 32];    // e^T tile [p][c pad 32], 64B rows        (16 KiB)

  const int t = threadIdx.x;
  const int lane = t & 63;
  const int wv = t >> 6;
  const int b = blockIdx.x >> 6;
  const int p0 = (blockIdx.x & 63) << 8;   // 256-pixel tile

  // ---- stage x^T: strided coalesced reads, b128 swizzled writes ----
  {
    const int cq = wv << 3;
#pragma unroll
    for (int half = 0; half < 2; ++half) {
      const int cc = cq + half * 32;
#pragma unroll
      for (int pp = 0; pp < 4; ++pp) {
        const int pl = pp * 64 + lane;
        const float* src = x + (size_t)(b * 64 + cc) * HW + p0 + pl;
        bf16x8 v;
#pragma unroll
        for (int i = 0; i < 8; ++i) v[i] = f2b(src[(size_t)i * HW]);
        int byte = pl * 128 + cc * 2;
        byte ^= (pl & 7) << 4;
        *reinterpret_cast<bf16x8*>(reinterpret_cast<char*>(lx) + byte) = v;
      }
    }
  }
  // ---- stage e^T, channels padded 16->32 with zeros ----
  {
    const int cq = (t & 3) << 3;
    const int pb = t >> 2;
#pragma unroll
    for (int pp = 0; pp < 4; ++pp) {
      const int pl = pp * 64 + pb;
      bf16x8 v;
#pragma unroll
      for (int i = 0; i < 8; ++i) {
        const int c = cq + i;
        float f = (c < 16) ? e[(size_t)(b * 16 + c) * HW + p0 + pl] : 0.0f;
        v[i] = f2b(f);
      }
      *reinterpret_cast<bf16x8*>(reinterpret_cast<char*>(le) + pl * 64 + cq * 2) = v;
    }
  }
  __syncthreads();

  const int pw0 = wv << 6;                 // wave's 64-pixel slice
  const int lr = lane & 15;
  const int lg = lane >> 4;
  const int kq = lg << 3;

  auto ldx = [&](int row, int c) -> bf16x8 {
    int byte = row * 128 + c * 2;
    byte ^= (row & 7) << 4;
    return *reinterpret_cast<const bf16x8*>(reinterpret_cast<const char*>(lx) + byte);
  };

  f32x4 acc[4][4];

  auto do_xtarget = [&](const float* __restrict__ Wm, const float* __restrict__ bias,
                        bf16_t* __restrict__ G) {
#pragma unroll
    for (int mt = 0; mt < 4; ++mt)
#pragma unroll
      for (int nt = 0; nt < 4; ++nt) acc[mt][nt] = f32x4{0.f, 0.f, 0.f, 0.f};
#pragma unroll
    for (int kt = 0; kt < 2; ++kt) {
      bf16x8 Bw[4], Af[4];
#pragma unroll
      for (int nt = 0; nt < 4; ++nt) {
        const float* wp = Wm + (size_t)(nt * 16 + lr) * 64 + kt * 32 + kq;
        bf16x8 a;
#pragma unroll
        for (int i = 0; i < 8; ++i) a[i] = f2b(wp[i]);
        Bw[nt] = a;
      }
#pragma unroll
      for (int mt = 0; mt < 4; ++mt) Af[mt] = ldx(pw0 + mt * 16 + lr, kt * 32 + kq);
#pragma unroll
      for (int mt = 0; mt < 4; ++mt)
#pragma unroll
        for (int nt = 0; nt < 4; ++nt)
          acc[mt][nt] = __builtin_amdgcn_mfma_f32_16x16x32_bf16(Af[mt], Bw[nt], acc[mt][nt], 0, 0, 0);
    }
    float bvv[4];
#pragma unroll
    for (int nt = 0; nt < 4; ++nt) bvv[nt] = bias[nt * 16 + lr];
#pragma unroll
    for (int nt = 0; nt < 4; ++nt)
#pragma unroll
      for (int mt = 0; mt < 4; ++mt) {
        u16x4_t pk;
#pragma unroll
        for (int r = 0; r < 4; ++r) pk[r] = b2u(f2b(acc[mt][nt][r] + bvv[nt]));
        *reinterpret_cast<u16x4_t*>(G + (size_t)(b * 64 + nt * 16 + lr) * HW
                                      + p0 + pw0 + mt * 16 + (lg << 2)) = pk;
      }
  };

  do_xtarget(W2, b2, Vg);   // V
  do_xtarget(W3, b3, Kg);   // K

  // ===== Q (W1, K-dim 16 padded to 32, e^T source) =====
#pragma unroll
  for (int mt = 0; mt < 4; ++mt)
#pragma unroll
    for (int nt = 0; nt < 4; ++nt) acc[mt][nt] = f32x4{0.f, 0.f, 0.f, 0.f};
  {
    bf16x8 Bw[4], Af[4];
#pragma unroll
    for (int nt = 0; nt < 4; ++nt) {
      bf16x8 a;
      if (kq < 16) {
        const float* wp = W1 + (size_t)(nt * 16 + lr) * 16 + kq;
#pragma unroll
        for (int i = 0; i < 8; ++i) a[i] = f2b(wp[i]);
      } else {
#pragma unroll
        for (int i = 0; i < 8; ++i) a[i] = f2b(0.0f);
      }
      Bw[nt] = a;
    }
#pragma unroll
    for (int mt = 0; mt < 4; ++mt)
      Af[mt] = *reinterpret_cast<const bf16x8*>(
          reinterpret_cast<const char*>(le) + (pw0 + mt * 16 + lr) * 64 + kq * 2);
#pragma unroll
    for (int mt = 0; mt < 4; ++mt)
#pragma unroll
      for (int nt = 0; nt < 4; ++nt)
        acc[mt][nt] = __builtin_amdgcn_mfma_f32_16x16x32_bf16(Af[mt], Bw[nt], acc[mt][nt], 0, 0, 0);
  }
  {
    float bvv[4];
#pragma unroll
    for (int nt = 0; nt < 4; ++nt) bvv[nt] = b1[nt * 16 + lr];
#pragma unroll
    for (int nt = 0; nt < 4; ++nt)
#pragma unroll
      for (int mt = 0; mt < 4; ++mt) {
        u16x4_t pk;
#pragma unroll
        for (int r = 0; r < 4; ++r) pk[r] = b2u(f2b(acc[mt][nt][r] + bvv[nt]));
        *reinterpret_cast<u16x4_t*>(Qg + (size_t)(b * 64 + nt * 16 + lr) * HW
                                      + p0 + pw0 + mt * 16 + (lg << 2)) = pk;
      }
  }
}

// ---------------- Phase 2: per-n attention; Q in regs, K^T staged up-front, ctx^T PV -------
__global__ __launch_bounds__(256, 2) void attn_kernel(
    const bf16_t* __restrict__ Qg, const bf16_t* __restrict__ Vg,
    const bf16_t* __restrict__ Kg, float* __restrict__ out)
{
  __shared__ bf16_t bufK[128 * 128];   // K^T [w][g]          (32 KiB)
  __shared__ bf16_t bufV[128 * 128];   // V [g][w], then P    (32 KiB)
  __shared__ float zl[128];            // 1/Z per h-row       (512 B)

  const int n = blockIdx.x;
  const int t = threadIdx.x;
  const int lane = t & 63;
  const int wv = t >> 6;
  const int lr = lane & 15;
  const int lg = lane >> 4;
  const int kq = lg << 3;
  const int h0 = wv << 5;              // wave's 32-row block (h for S/P, w for PV A-side)

  const bf16_t* Qn = Qg + (size_t)n * HW;
  const bf16_t* Vn = Vg + (size_t)n * HW;
  const bf16_t* Kn = Kg + (size_t)n * HW;

  // Q A-fragments straight from global (wave-private rows) — overlaps staging
  bf16x8 qf[4][2];
#pragma unroll
  for (int kt = 0; kt < 4; ++kt)
#pragma unroll
    for (int mt = 0; mt < 2; ++mt)
      qf[kt][mt] = *reinterpret_cast<const bf16x8*>(
          Qn + (h0 + mt * 16 + lr) * 128 + kt * 32 + kq);

  // stage V rows (coalesced b128, swizzled)
#pragma unroll
  for (int it = 0; it < 8; ++it) {
    const int chunk = it * 256 + t;
    const int row = chunk >> 4;
    int byte = (row << 8) + ((chunk & 15) << 4);
    byte ^= (row & 7) << 4;
    *reinterpret_cast<bf16x8*>(reinterpret_cast<char*>(bufV) + byte) =
        *reinterpret_cast<const bf16x8*>(Vn + chunk * 8);
  }
  // stage K^T up-front (coalesced strided u16 reads, b128 swizzled writes)
#pragma unroll
  for (int it = 0; it < 8; ++it) {
    const int w = t & 127;
    const int g0 = ((it << 1) + (t >> 7)) << 3;
    bf16x8 v;
#pragma unroll
    for (int i = 0; i < 8; ++i) v[i] = Kn[(g0 + i) * 128 + w];
    int byte = (w << 8) + (g0 << 1);
    byte ^= (w & 7) << 4;
    *reinterpret_cast<bf16x8*>(reinterpret_cast<char*>(bufK) + byte) = v;
  }
  __syncthreads();

  auto ldfrag = [&](const bf16_t* buf, int row, int c) -> bf16x8 {
    int byte = (row << 8) + (c << 1);
    byte ^= (row & 7) << 4;
    return *reinterpret_cast<const bf16x8*>(reinterpret_cast<const char*>(buf) + byte);
  };

  // S = Q V^T   (A=Q rows h [regs], B=V rows g [LDS])
  f32x4 acc[2][8];
#pragma unroll
  for (int mt = 0; mt < 2; ++mt)
#pragma unroll
    for (int nt = 0; nt < 8; ++nt) acc[mt][nt] = f32x4{0.f, 0.f, 0.f, 0.f};
#pragma unroll
  for (int kt = 0; kt < 4; ++kt) {
#pragma unroll
    for (int nt = 0; nt < 8; ++nt) {
      bf16x8 Bv = ldfrag(bufV, nt * 16 + lr, kt * 32 + kq);
      acc[0][nt] = __builtin_amdgcn_mfma_f32_16x16x32_bf16(qf[kt][0], Bv, acc[0][nt], 0, 0, 0);
      acc[1][nt] = __builtin_amdgcn_mfma_f32_16x16x32_bf16(qf[kt][1], Bv, acc[1][nt], 0, 0, 0);
    }
  }

  // row softmax over g; keep P unnormalized, 1/Z deferred via LDS
  float zrow[2][4];
#pragma unroll
  for (int mt = 0; mt < 2; ++mt) {
#pragma unroll
    for (int r = 0; r < 4; ++r) {
      float m = acc[mt][0][r];
#pragma unroll
      for (int nt = 1; nt < 8; ++nt) m = fmaxf(m, acc[mt][nt][r]);
      m = fmaxf(m, __shfl_xor(m, 1));
      m = fmaxf(m, __shfl_xor(m, 2));
      m = fmaxf(m, __shfl_xor(m, 4));
      m = fmaxf(m, __shfl_xor(m, 8));
      float z = 0.f;
#pragma unroll
      for (int nt = 0; nt < 8; ++nt) {
        float p = exp2f((acc[mt][nt][r] - m) * LOG2E);
        acc[mt][nt][r] = p;
        z += p;
      }
      z += __shfl_xor(z, 1);
      z += __shfl_xor(z, 2);
      z += __shfl_xor(z, 4);
      z += __shfl_xor(z, 8);
      zrow[mt][r] = z;
    }
  }
  __syncthreads();   // all waves done reading V from LDS

  // write P (own 32 rows) into bufV; 1/Z into zl
#pragma unroll
  for (int mt = 0; mt < 2; ++mt) {
    const int rbase = h0 + mt * 16 + (lg << 2);
    if (lr == 0) {
#pragma unroll
      for (int r = 0; r < 4; ++r) zl[rbase + r] = 1.0f / zrow[mt][r];
    }
#pragma unroll
    for (int nt = 0; nt < 8; ++nt) {
#pragma unroll
      for (int r = 0; r < 4; ++r) {
        const int row = rbase + r;
        int byte = (row << 8) + ((nt * 16 + lr) << 1);
        byte ^= (row & 7) << 4;
        *reinterpret_cast<bf16_t*>(reinterpret_cast<char*>(bufV) + byte) = f2b(acc[mt][nt][r]);
      }
    }
  }
  __syncthreads();

  // ctx^T: D'[w][h] = sum_g K^T[w,g] P[h,g]   (A=K^T rows w [own 32], B=P rows h [all])
  f32x4 acc2[2][8];
#pragma unroll
  for (int mt = 0; mt < 2; ++mt)
#pragma unroll
    for (int nt = 0; nt < 8; ++nt) acc2[mt][nt] = f32x4{0.f, 0.f, 0.f, 0.f};
#pragma unroll
  for (int kt = 0; kt < 4; ++kt) {
    bf16x8 A0 = ldfrag(bufK, h0 + lr,      kt * 32 + kq);
    bf16x8 A1 = ldfrag(bufK, h0 + 16 + lr, kt * 32 + kq);
#pragma unroll
    for (int nt = 0; nt < 8; ++nt) {
      bf16x8 Bp = ldfrag(bufV, nt * 16 + lr, kt * 32 + kq);
      acc2[0][nt] = __builtin_amdgcn_mfma_f32_16x16x32_bf16(A0, Bp, acc2[0][nt], 0, 0, 0);
      acc2[1][nt] = __builtin_amdgcn_mfma_f32_16x16x32_bf16(A1, Bp, acc2[1][nt], 0, 0, 0);
    }
  }

  // store: out[h][w], h = nt*16+lr (col), w = h0 + mt*16 + 4*lg + r (row) -> f32x4 along w
  float* On = out + (size_t)n * HW;
#pragma unroll
  for (int nt = 0; nt < 8; ++nt) {
    const float zv = zl[nt * 16 + lr];
#pragma unroll
    for (int mt = 0; mt < 2; ++mt) {
      f32x4 o;
#pragma unroll
      for (int r = 0; r < 4; ++r) o[r] = acc2[mt][nt][r] * zv;
      *reinterpret_cast<f32x4*>(On + (size_t)(nt * 16 + lr) * 128
                                + h0 + mt * 16 + (lg << 2)) = o;
    }
  }
}

extern "C" void kernel_launch(void* const* d_in, const int* in_sizes, int n_in,
                              void* d_out, int out_size, void* d_ws, size_t ws_size,
                              hipStream_t stream) {
  const float* x  = (const float*)d_in[0];
  const float* e  = (const float*)d_in[1];
  const float* W1 = (const float*)d_in[2];
  const float* b1 = (const float*)d_in[3];
  const float* W2 = (const float*)d_in[4];
  const float* b2 = (const float*)d_in[5];
  const float* W3 = (const float*)d_in[6];
  const float* b3 = (const float*)d_in[7];
  float* out = (float*)d_out;

  bf16_t* Qg = (bf16_t*)d_ws;                       // 32 MiB each, 96 MiB total
  bf16_t* Vg = Qg + (size_t)1024 * HW;
  bf16_t* Kg = Vg + (size_t)1024 * HW;

  qvk_kernel<<<1024, 256, 0, stream>>>(x, e, W1, b1, W2, b2, W3, b3, Qg, Vg, Kg);
  attn_kernel<<<1024, 256, 0, stream>>>(Qg, Vg, Kg, out);
}

// Round 5
// 196.163 us; speedup vs baseline: 1.1004x; 1.1004x over previous
//
#include <hip/hip_runtime.h>

typedef __bf16 bf16_t;
typedef __bf16 bf16x8 __attribute__((ext_vector_type(8)));
typedef float f32x4 __attribute__((ext_vector_type(4)));
typedef unsigned short u16x4_t __attribute__((ext_vector_type(4)));

#define HW 16384
#define LOG2E 1.44269504088896f

__device__ __forceinline__ bf16_t f2b(float f) {
  unsigned u = __builtin_bit_cast(unsigned, f);
  u += 0x7fff + ((u >> 16) & 1);              // RTN-even
  unsigned short s = (unsigned short)(u >> 16);
  return __builtin_bit_cast(bf16_t, s);
}
__device__ __forceinline__ unsigned short b2u(bf16_t b) {
  return __builtin_bit_cast(unsigned short, b);
}
// swizzles: spread 16B (or sub-) chunks across banks; bijective per row.
// swz8: for 128B/256B rows (8x16B chunks) — conflict-free for 16-consecutive
// rows (fragment reads) AND stride-4 rows (transpose writes).
__device__ __forceinline__ int swz8(int row) { return ((row ^ (row >> 3)) & 7) << 4; }
// swz4v: for 64B rows (4x16B chunks), unshifted.
__device__ __forceinline__ int swz4v(int row) { return (row ^ (row >> 2)) & 3; }

// ---------------- Phase 1: Q/V/K 1x1-conv, all-prefetch, all-LDS GEMM ----------------
// D[p][o] = sum_c x^T[p,c] W[o,c]; C/D: col(N)=o=lane&15, row(M)=p=4*(lane>>4)+r
__global__ __launch_bounds__(256, 3) void qvk_kernel(
    const float* __restrict__ x, const float* __restrict__ e,
    const float* __restrict__ W1, const float* __restrict__ b1,
    const float* __restrict__ W2, const float* __restrict__ b2,
    const float* __restrict__ W3, const float* __restrict__ b3,
    bf16_t* __restrict__ Qg, bf16_t* __restrict__ Vg, bf16_t* __restrict__ Kg)
{
  __shared__ bf16_t lx[128 * 64];    // x^T [p][c]  128B rows, swz8   (16 KiB)
  __shared__ bf16_t le[128 * 32];    // e^T [p][c pad32] 64B rows     ( 8 KiB)
  __shared__ bf16_t w2b[64 * 64];    // W2 [o][c]   128B rows, swz8   ( 8 KiB)
  __shared__ bf16_t w3b[64 * 64];    // W3                            ( 8 KiB)
  __shared__ bf16_t w1b[64 * 32];    // W1 [o][c pad32] 64B rows      ( 4 KiB)

  const int t = threadIdx.x;
  const int lane = t & 63;
  const int wv = t >> 6;
  const int b = blockIdx.x >> 7;
  const int p0 = (blockIdx.x & 127) << 7;   // 128-pixel tile
  const int lr = lane & 15;
  const int lg = lane >> 4;
  const int kq = lg << 3;

  // ================= issue ALL global loads up-front (independent) =================
  const int li = lane & 31;
  const int h2 = lane >> 5;
  const int cbase = wv * 16 + h2 * 8;       // 8 consecutive c per thread
  f32x4 xr[8];
#pragma unroll
  for (int j = 0; j < 8; ++j)
    xr[j] = *reinterpret_cast<const f32x4*>(
        x + (size_t)(b * 64 + cbase + j) * HW + p0 + li * 4);

  const int ec = t >> 4;                    // e channel 0..15
  const int ep = (t & 15) * 4;
  f32x4 er[2];
#pragma unroll
  for (int j = 0; j < 2; ++j)
    er[j] = *reinterpret_cast<const f32x4*>(
        e + (size_t)(b * 16 + ec) * HW + p0 + ep + j * 64);

  const int wo = t >> 2;                    // 0..63
  const int wc = (t & 3) * 16;
  f32x4 w2r[4], w3r[4];
#pragma unroll
  for (int k = 0; k < 4; ++k) {
    w2r[k] = *reinterpret_cast<const f32x4*>(W2 + (size_t)wo * 64 + wc + k * 4);
    w3r[k] = *reinterpret_cast<const f32x4*>(W3 + (size_t)wo * 64 + wc + k * 4);
  }
  const int w1c = (t & 3) * 4;
  f32x4 w1r = *reinterpret_cast<const f32x4*>(W1 + (size_t)wo * 16 + w1c);

  float bv1[4], bv2[4], bv3[4];
#pragma unroll
  for (int nt = 0; nt < 4; ++nt) {
    bv1[nt] = b1[nt * 16 + lr];
    bv2[nt] = b2[nt * 16 + lr];
    bv3[nt] = b3[nt * 16 + lr];
  }

  // ================= LDS writes =================
  // x^T: 4 b128 writes; row = li*4+r, chunk = cbase/8
  {
    const int chunk = cbase >> 3;
#pragma unroll
    for (int r = 0; r < 4; ++r) {
      const int row = li * 4 + r;
      bf16x8 v;
#pragma unroll
      for (int j = 0; j < 8; ++j) v[j] = f2b(xr[j][r]);
      *reinterpret_cast<bf16x8*>(reinterpret_cast<char*>(lx)
          + row * 128 + ((chunk << 4) ^ swz8(row))) = v;
    }
  }
  // e^T: 8 scattered b16 writes (real channels 0..15)
#pragma unroll
  for (int j = 0; j < 2; ++j)
#pragma unroll
    for (int r = 0; r < 4; ++r) {
      const int row = ep + j * 64 + r;
      const int byte = row * 64 + ((((ec >> 3) ^ swz4v(row)) << 4)) + (ec & 7) * 2;
      *reinterpret_cast<bf16_t*>(reinterpret_cast<char*>(le) + byte) = f2b(er[j][r]);
    }
  // e^T zero-pad channels 16..31: one b128 zero per thread
  {
    const int row = t >> 1;
    const int chunk = 2 + (t & 1);
    bf16x8 zv;
#pragma unroll
    for (int k = 0; k < 8; ++k) zv[k] = f2b(0.0f);
    *reinterpret_cast<bf16x8*>(reinterpret_cast<char*>(le)
        + row * 64 + ((chunk ^ swz4v(row)) << 4)) = zv;
  }
  // W2/W3: 2 b128 writes each
  {
    const int ch0 = (t & 3) * 2;
    bf16x8 a, c2;
#pragma unroll
    for (int k = 0; k < 8; ++k) {
      a[k]  = f2b(w2r[k >> 2][k & 3]);
      c2[k] = f2b(w2r[2 + (k >> 2)][k & 3]);
    }
    *reinterpret_cast<bf16x8*>(reinterpret_cast<char*>(w2b)
        + wo * 128 + ((ch0 << 4) ^ swz8(wo))) = a;
    *reinterpret_cast<bf16x8*>(reinterpret_cast<char*>(w2b)
        + wo * 128 + (((ch0 + 1) << 4) ^ swz8(wo))) = c2;
#pragma unroll
    for (int k = 0; k < 8; ++k) {
      a[k]  = f2b(w3r[k >> 2][k & 3]);
      c2[k] = f2b(w3r[2 + (k >> 2)][k & 3]);
    }
    *reinterpret_cast<bf16x8*>(reinterpret_cast<char*>(w3b)
        + wo * 128 + ((ch0 << 4) ^ swz8(wo))) = a;
    *reinterpret_cast<bf16x8*>(reinterpret_cast<char*>(w3b)
        + wo * 128 + (((ch0 + 1) << 4) ^ swz8(wo))) = c2;
  }
  // W1: one b64 write (8B, within a 16B chunk) + zero-pad chunks
  {
    typedef __bf16 bf16x4_ __attribute__((ext_vector_type(4)));
    bf16x4_ a;
#pragma unroll
    for (int k = 0; k < 4; ++k) a[k] = f2b(w1r[k]);
    const int byte = wo * 64 + (((w1c >> 3) ^ swz4v(wo)) << 4) + (w1c & 4) * 2;
    *reinterpret_cast<bf16x4_*>(reinterpret_cast<char*>(w1b) + byte) = a;
    if (t < 128) {
      const int row = t >> 1;
      const int chunk = 2 + (t & 1);
      bf16x8 zv;
#pragma unroll
      for (int k = 0; k < 8; ++k) zv[k] = f2b(0.0f);
      *reinterpret_cast<bf16x8*>(reinterpret_cast<char*>(w1b)
          + row * 64 + ((chunk ^ swz4v(row)) << 4)) = zv;
    }
  }
  __syncthreads();

  // ================= GEMMs (all operands in LDS) =================
  const int pw0 = wv << 5;                  // wave's 32-pixel slice

  auto ldx = [&](int row, int ce) -> bf16x8 {
    return *reinterpret_cast<const bf16x8*>(reinterpret_cast<const char*>(lx)
        + row * 128 + (((ce >> 3) << 4) ^ swz8(row)));
  };
  auto ldw = [&](const bf16_t* wb, int row, int ce) -> bf16x8 {
    return *reinterpret_cast<const bf16x8*>(reinterpret_cast<const char*>(wb)
        + row * 128 + (((ce >> 3) << 4) ^ swz8(row)));
  };
  auto ld64 = [&](const bf16_t* buf, int row, int ce) -> bf16x8 {
    return *reinterpret_cast<const bf16x8*>(reinterpret_cast<const char*>(buf)
        + row * 64 + (((ce >> 3) ^ swz4v(row)) << 4));
  };

  f32x4 acc[2][4];

  auto do_xtarget = [&](const bf16_t* wb, const float* bvv, bf16_t* __restrict__ G) {
#pragma unroll
    for (int mt = 0; mt < 2; ++mt)
#pragma unroll
      for (int nt = 0; nt < 4; ++nt) acc[mt][nt] = f32x4{0.f, 0.f, 0.f, 0.f};
#pragma unroll
    for (int kt = 0; kt < 2; ++kt) {
      bf16x8 Af[2], Bw[4];
#pragma unroll
      for (int mt = 0; mt < 2; ++mt) Af[mt] = ldx(pw0 + mt * 16 + lr, kt * 32 + kq);
#pragma unroll
      for (int nt = 0; nt < 4; ++nt) Bw[nt] = ldw(wb, nt * 16 + lr, kt * 32 + kq);
#pragma unroll
      for (int mt = 0; mt < 2; ++mt)
#pragma unroll
        for (int nt = 0; nt < 4; ++nt)
          acc[mt][nt] = __builtin_amdgcn_mfma_f32_16x16x32_bf16(Af[mt], Bw[nt], acc[mt][nt], 0, 0, 0);
    }
#pragma unroll
    for (int nt = 0; nt < 4; ++nt)
#pragma unroll
      for (int mt = 0; mt < 2; ++mt) {
        u16x4_t pk;
#pragma unroll
        for (int r = 0; r < 4; ++r) pk[r] = b2u(f2b(acc[mt][nt][r] + bvv[nt]));
        *reinterpret_cast<u16x4_t*>(G + (size_t)(b * 64 + nt * 16 + lr) * HW
                                      + p0 + pw0 + mt * 16 + (lg << 2)) = pk;
      }
  };

  do_xtarget(w2b, bv2, Vg);   // V
  do_xtarget(w3b, bv3, Kg);   // K

  // Q (K-dim 16 padded to 32 with zeros on both operands)
#pragma unroll
  for (int mt = 0; mt < 2; ++mt)
#pragma unroll
    for (int nt = 0; nt < 4; ++nt) acc[mt][nt] = f32x4{0.f, 0.f, 0.f, 0.f};
  {
    bf16x8 Af[2], Bw[4];
#pragma unroll
    for (int mt = 0; mt < 2; ++mt) Af[mt] = ld64(le, pw0 + mt * 16 + lr, kq);
#pragma unroll
    for (int nt = 0; nt < 4; ++nt) Bw[nt] = ld64(w1b, nt * 16 + lr, kq);
#pragma unroll
    for (int mt = 0; mt < 2; ++mt)
#pragma unroll
      for (int nt = 0; nt < 4; ++nt)
        acc[mt][nt] = __builtin_amdgcn_mfma_f32_16x16x32_bf16(Af[mt], Bw[nt], acc[mt][nt], 0, 0, 0);
  }
#pragma unroll
  for (int nt = 0; nt < 4; ++nt)
#pragma unroll
    for (int mt = 0; mt < 2; ++mt) {
      u16x4_t pk;
#pragma unroll
      for (int r = 0; r < 4; ++r) pk[r] = b2u(f2b(acc[mt][nt][r] + bv1[nt]));
      *reinterpret_cast<u16x4_t*>(Qg + (size_t)(b * 64 + nt * 16 + lr) * HW
                                    + p0 + pw0 + mt * 16 + (lg << 2)) = pk;
    }
}

// ---------------- Phase 2: attention; all loads up-front, K^T scatter deferred under S ----
__global__ __launch_bounds__(256, 2) void attn_kernel(
    const bf16_t* __restrict__ Qg, const bf16_t* __restrict__ Vg,
    const bf16_t* __restrict__ Kg, float* __restrict__ out)
{
  __shared__ bf16_t bufK[128 * 128];   // K^T [w][g], swz8   (32 KiB)
  __shared__ bf16_t bufV[128 * 128];   // V [g][w] then P    (32 KiB)
  __shared__ float zl[128];            // 1/Z per h-row

  const int n = blockIdx.x;
  const int t = threadIdx.x;
  const int lane = t & 63;
  const int wv = t >> 6;
  const int lr = lane & 15;
  const int lg = lane >> 4;
  const int kq = lg << 3;
  const int h0 = wv << 5;

  const bf16_t* Qn = Qg + (size_t)n * HW;
  const bf16_t* Vn = Vg + (size_t)n * HW;
  const bf16_t* Kn = Kg + (size_t)n * HW;

  // ---- issue ALL global loads up-front: V(8) -> K(8) -> Q(8), all bf16x8 coalesced ----
  bf16x8 vreg[8];
#pragma unroll
  for (int it = 0; it < 8; ++it)
    vreg[it] = *reinterpret_cast<const bf16x8*>(Vn + (it * 256 + t) * 8);

  const int wchunk = t & 15;           // K: row g = (t>>4)+16*it, cols wchunk*8..+7
  const int grow = t >> 4;
  bf16x8 kreg[8];
#pragma unroll
  for (int it = 0; it < 8; ++it)
    kreg[it] = *reinterpret_cast<const bf16x8*>(Kn + (grow + 16 * it) * 128 + wchunk * 8);

  bf16x8 qf[4][2];
#pragma unroll
  for (int kt = 0; kt < 4; ++kt)
#pragma unroll
    for (int mt = 0; mt < 2; ++mt)
      qf[kt][mt] = *reinterpret_cast<const bf16x8*>(
          Qn + (h0 + mt * 16 + lr) * 128 + kt * 32 + kq);

  // ---- stage V (b128 swizzled writes) ----
#pragma unroll
  for (int it = 0; it < 8; ++it) {
    const int chunk = it * 256 + t;
    const int row = chunk >> 4;
    *reinterpret_cast<bf16x8*>(reinterpret_cast<char*>(bufV)
        + row * 256 + (((chunk & 15) << 4) ^ swz8(row))) = vreg[it];
  }
  __syncthreads();

  auto ldfrag = [&](const bf16_t* buf, int row, int c) -> bf16x8 {
    return *reinterpret_cast<const bf16x8*>(reinterpret_cast<const char*>(buf)
        + row * 256 + (((c << 1)) ^ swz8(row)));
  };

  // ---- S = Q V^T ----
  f32x4 acc[2][8];
#pragma unroll
  for (int mt = 0; mt < 2; ++mt)
#pragma unroll
    for (int nt = 0; nt < 8; ++nt) acc[mt][nt] = f32x4{0.f, 0.f, 0.f, 0.f};
#pragma unroll
  for (int kt = 0; kt < 4; ++kt) {
#pragma unroll
    for (int nt = 0; nt < 8; ++nt) {
      bf16x8 Bv = ldfrag(bufV, nt * 16 + lr, kt * 32 + kq);
      acc[0][nt] = __builtin_amdgcn_mfma_f32_16x16x32_bf16(qf[kt][0], Bv, acc[0][nt], 0, 0, 0);
      acc[1][nt] = __builtin_amdgcn_mfma_f32_16x16x32_bf16(qf[kt][1], Bv, acc[1][nt], 0, 0, 0);
    }
  }

  // ---- K^T transpose-scatter into bufK (HBM latency already hidden under S) ----
#pragma unroll
  for (int it = 0; it < 8; ++it) {
    const int g = grow + 16 * it;
#pragma unroll
    for (int j = 0; j < 8; ++j) {
      const int w = wchunk * 8 + j;
      *reinterpret_cast<bf16_t*>(reinterpret_cast<char*>(bufK)
          + w * 256 + ((g << 1) ^ swz8(w))) = kreg[it][j];
    }
  }

  // ---- row softmax (unnormalized P, deferred 1/Z) ----
  float zrow[2][4];
#pragma unroll
  for (int mt = 0; mt < 2; ++mt) {
#pragma unroll
    for (int r = 0; r < 4; ++r) {
      float m = acc[mt][0][r];
#pragma unroll
      for (int nt = 1; nt < 8; ++nt) m = fmaxf(m, acc[mt][nt][r]);
      m = fmaxf(m, __shfl_xor(m, 1));
      m = fmaxf(m, __shfl_xor(m, 2));
      m = fmaxf(m, __shfl_xor(m, 4));
      m = fmaxf(m, __shfl_xor(m, 8));
      float z = 0.f;
#pragma unroll
      for (int nt = 0; nt < 8; ++nt) {
        float p = exp2f((acc[mt][nt][r] - m) * LOG2E);
        acc[mt][nt][r] = p;
        z += p;
      }
      z += __shfl_xor(z, 1);
      z += __shfl_xor(z, 2);
      z += __shfl_xor(z, 4);
      z += __shfl_xor(z, 8);
      zrow[mt][r] = z;
    }
  }
  __syncthreads();   // all waves done reading V

  // ---- write P into bufV; 1/Z into zl ----
#pragma unroll
  for (int mt = 0; mt < 2; ++mt) {
    const int rbase = h0 + mt * 16 + (lg << 2);
    if (lr == 0) {
#pragma unroll
      for (int r = 0; r < 4; ++r) zl[rbase + r] = 1.0f / zrow[mt][r];
    }
#pragma unroll
    for (int nt = 0; nt < 8; ++nt) {
#pragma unroll
      for (int r = 0; r < 4; ++r) {
        const int row = rbase + r;
        *reinterpret_cast<bf16_t*>(reinterpret_cast<char*>(bufV)
            + row * 256 + (((nt * 16 + lr) << 1) ^ swz8(row))) = f2b(acc[mt][nt][r]);
      }
    }
  }
  __syncthreads();

  // ---- ctx^T: D'[w][h] = sum_g K^T[w,g] P[h,g] ----
  f32x4 acc2[2][8];
#pragma unroll
  for (int mt = 0; mt < 2; ++mt)
#pragma unroll
    for (int nt = 0; nt < 8; ++nt) acc2[mt][nt] = f32x4{0.f, 0.f, 0.f, 0.f};
#pragma unroll
  for (int kt = 0; kt < 4; ++kt) {
    bf16x8 A0 = ldfrag(bufK, h0 + lr,      kt * 32 + kq);
    bf16x8 A1 = ldfrag(bufK, h0 + 16 + lr, kt * 32 + kq);
#pragma unroll
    for (int nt = 0; nt < 8; ++nt) {
      bf16x8 Bp = ldfrag(bufV, nt * 16 + lr, kt * 32 + kq);
      acc2[0][nt] = __builtin_amdgcn_mfma_f32_16x16x32_bf16(A0, Bp, acc2[0][nt], 0, 0, 0);
      acc2[1][nt] = __builtin_amdgcn_mfma_f32_16x16x32_bf16(A1, Bp, acc2[1][nt], 0, 0, 0);
    }
  }

  // ---- store out[h][w] with f32x4 along w ----
  float* On = out + (size_t)n * HW;
#pragma unroll
  for (int nt = 0; nt < 8; ++nt) {
    const float zv = zl[nt * 16 + lr];
#pragma unroll
    for (int mt = 0; mt < 2; ++mt) {
      f32x4 o;
#pragma unroll
      for (int r = 0; r < 4; ++r) o[r] = acc2[mt][nt][r] * zv;
      *reinterpret_cast<f32x4*>(On + (size_t)(nt * 16 + lr) * 128
                                + h0 + mt * 16 + (lg << 2)) = o;
    }
  }
}

extern "C" void kernel_launch(void* const* d_in, const int* in_sizes, int n_in,
                              void* d_out, int out_size, void* d_ws, size_t ws_size,
                              hipStream_t stream) {
  const float* x  = (const float*)d_in[0];
  const float* e  = (const float*)d_in[1];
  const float* W1 = (const float*)d_in[2];
  const float* b1 = (const float*)d_in[3];
  const float* W2 = (const float*)d_in[4];
  const float* b2 = (const float*)d_in[5];
  const float* W3 = (const float*)d_in[6];
  const float* b3 = (const float*)d_in[7];
  float* out = (float*)d_out;

  bf16_t* Qg = (bf16_t*)d_ws;                       // 32 MiB each, 96 MiB total
  bf16_t* Vg = Qg + (size_t)1024 * HW;
  bf16_t* Kg = Vg + (size_t)1024 * HW;

  qvk_kernel<<<2048, 256, 0, stream>>>(x, e, W1, b1, W2, b2, W3, b3, Qg, Vg, Kg);
  attn_kernel<<<1024, 256, 0, stream>>>(Qg, Vg, Kg, out);
}